// Round 6
// baseline (207.174 us; speedup 1.0000x reference)
//
#include <hip/hip_runtime.h>
#include <cstdint>

// y = clip(round((x @ W^T) * (sx*sw/sy)), -128, 127), M=8192 N=4096 K=4096 int8.
// Pass 1 (pack): int32 -> int8, permuted to MFMA-fragment-major:
//   per (256-row block, 16KB K-half-tile h=0..63): [rf 0..15][lane*16],
//   lane = kl*16+fr holds rows rf*16+fr, K-bytes h*64 + kl*16..+15
//   (exact mfma_i32_16x16x64_i8 operand order). Conflict-free ds_read_b128.
// Pass 2 (GEMM): 256x256 block tile, 4 waves (2Mx2N quadrants, 128x128 each).
//   BARRIER-FREE main loop: each wave stages its OWN A-half + B-half fragments
//   into a PRIVATE 32KB LDS ring-2 (4 x 32KB = 128KB) via global_load_lds,
//   synchronized only by per-wave counted s_waitcnt vmcnt(16) (never 0
//   mid-loop). No cross-wave LDS deps -> no s_barrier -> waves drift, LDS
//   traffic overlaps MFMA naturally. Cost: A/B staged 2x (L2 absorbs).

#define MDIM 8192
#define NDIM 4096
#define KDIM 4096
#define BM 256
#define BN 256
#define NH 64  // 64 half-tiles of K=64 bytes

typedef int v4i __attribute__((ext_vector_type(4)));

__device__ __forceinline__ uint32_t pack4(int a, int b, int c, int d) {
  return (uint32_t)(a & 0xFF) | ((uint32_t)(b & 0xFF) << 8) |
         ((uint32_t)(c & 0xFF) << 16) | ((uint32_t)(d & 0xFF) << 24);
}

// ---------- pack: gather int32 -> fragment-major int8 + scale_y tail ----------
// Layout per source matrix: [mb (256 rows)][h=0..63 (K/64)][rf 0..15][64*16B]
__global__ __launch_bounds__(256) void pack_kernel(
    const int* __restrict__ x32, const int* __restrict__ w32,
    const float* __restrict__ sy, uint8_t* __restrict__ x8f,
    uint8_t* __restrict__ w8f, float* __restrict__ tail) {
  const int t = blockIdx.x * 256 + threadIdx.x;
  if (t < NDIM) tail[t] = sy[t];
  const int NXC = (MDIM / 16) * KDIM;  // 2,097,152 16B-chunks for x
  const int NWC = (NDIM / 16) * KDIM;  // 1,048,576 for w
  if (t >= NXC + NWC) return;
  const int* src;
  uint8_t* dst;
  int chunk;
  if (t < NXC) {
    chunk = t;
    src = x32;
    dst = x8f;
  } else {
    chunk = t - NXC;
    src = w32;
    dst = w8f;
  }
  // chunk -> [mb][h][rf][lane], 16B per lane slot
  const int lpos = chunk & 63;          // lane
  const int rf = (chunk >> 6) & 15;     // 16-row fragment
  const int h = (chunk >> 10) & 63;     // K-half-tile (64 bytes)
  const int mb = chunk >> 16;           // 256-row block
  const int kl = lpos >> 4, fr = lpos & 15;
  const int r = mb * 256 + rf * 16 + fr;
  const int k0 = h * 64 + kl * 16;
  const int* s = src + (size_t)r * KDIM + k0;  // 16 int32 = 64B line
  v4i a0 = *(const v4i*)(s + 0);
  v4i a1 = *(const v4i*)(s + 4);
  v4i a2 = *(const v4i*)(s + 8);
  v4i a3 = *(const v4i*)(s + 12);
  v4i o;
  o[0] = (int)pack4(a0[0], a0[1], a0[2], a0[3]);
  o[1] = (int)pack4(a1[0], a1[1], a1[2], a1[3]);
  o[2] = (int)pack4(a2[0], a2[1], a2[2], a2[3]);
  o[3] = (int)pack4(a3[0], a3[1], a3[2], a3[3]);
  *(v4i*)(dst + (size_t)chunk * 16) = o;  // linear, fully coalesced
}

// ---------- main GEMM ----------------------------------------------------------
// 256 threads = 4 waves (2M x 2N), per-wave output 128x128, acc 8x8 frags.
// Per-wave private LDS: wave*32768 + [ring 0/1: 16KB][A 8KB][B 8KB].
__global__ __launch_bounds__(256, 1) void gemm_kernel(
    const uint8_t* __restrict__ A8, const uint8_t* __restrict__ B8,
    const float* __restrict__ sxp, const float* __restrict__ swp,
    const float* __restrict__ syp, float* __restrict__ out) {
  __shared__ __align__(16) uint8_t lds[131072];

  const int tid = threadIdx.x;
  const int lane = tid & 63;
  const int wave = tid >> 6;  // 0..3

  // XCD-aware swizzle: nwg = 512 (divisible by 8 -> bijective).
  // 16 consecutive blocks on an XCD share one A-panel (1MB, L2-resident).
  const int wg = ((int)blockIdx.x % 8) * 64 + (int)blockIdx.x / 8;
  const int mb = wg >> 4;  // 0..31
  const int nb = wg & 15;  // 0..15

  const int wm2 = wave >> 1;  // M-half
  const int wn2 = wave & 1;   // N-half

  // per half-tile h: wave's A rows at Asrc + h*16384 (8KB), B cols likewise
  const uint8_t* Asrc = A8 + ((size_t)mb << 20) + ((size_t)wm2 << 13);
  const uint8_t* Bsrc = B8 + ((size_t)nb << 20) + ((size_t)wn2 << 13);

  uint8_t* wlds = lds + wave * 32768;
  const uint32_t lane16 = (uint32_t)lane * 16;

  v4i acc[8][8];
#pragma unroll
  for (int i = 0; i < 8; i++)
#pragma unroll
    for (int j = 0; j < 8; j++) acc[i][j] = (v4i){0, 0, 0, 0};

  auto gload = [&](const uint8_t* src, uint8_t* ldst) {
    __builtin_amdgcn_global_load_lds(
        (const __attribute__((address_space(1))) void*)src,
        (__attribute__((address_space(3))) void*)ldst, 16, 0, 0);
  };
  // stage wave's own 16KB (A-half 8KB + B-half 8KB) for half-tile h
  auto stage = [&](int h) {
    const uint32_t rb = (uint32_t)(h & 1) * 16384u;
    const uint8_t* sa = Asrc + ((size_t)h << 14) + lane16;
    const uint8_t* sb = Bsrc + ((size_t)h << 14) + lane16;
    uint8_t* la = wlds + rb + lane16;
#pragma unroll
    for (int r = 0; r < 8; ++r) {
      gload(sa + r * 1024, la + r * 1024);
      gload(sb + r * 1024, la + 8192 + r * 1024);
    }
  };

  stage(0);  // 16 loads in flight

  for (int h = 0; h < NH; ++h) {
    if (h + 1 < NH) {
      stage(h + 1);  // 32 outstanding; oldest 16 = half-tile h
      asm volatile("s_waitcnt vmcnt(16)" ::: "memory");
    } else {
      asm volatile("s_waitcnt vmcnt(0)" ::: "memory");
    }
    const uint8_t* LA = wlds + (uint32_t)(h & 1) * 16384u;
    const uint8_t* LB = LA + 8192;

    v4i af[8], bf[8];
#pragma unroll
    for (int i = 0; i < 8; i++)
      af[i] = *(const v4i*)(LA + (i << 10) + lane16);
#pragma unroll
    for (int j = 0; j < 8; j++)
      bf[j] = *(const v4i*)(LB + (j << 10) + lane16);

#pragma unroll
    for (int i = 0; i < 8; i++)
#pragma unroll
      for (int j = 0; j < 8; j++)
        acc[i][j] =
            __builtin_amdgcn_mfma_i32_16x16x64_i8(af[i], bf[j], acc[i][j], 0, 0, 0);
  }

  // epilogue: requantize, round-half-even, clip, store float
  const float s = sxp[0] * swp[0];
  const int kl = lane >> 4;
  const int fr = lane & 15;
  const int wrow = mb * 256 + wm2 * 128;
  const int wcol = nb * 256 + wn2 * 128;
#pragma unroll
  for (int j = 0; j < 8; j++) {
    const int col = wcol + j * 16 + fr;
    const float rs = s / syp[col];
#pragma unroll
    for (int i = 0; i < 8; i++) {
      const int row0 = wrow + i * 16 + kl * 4;
#pragma unroll
      for (int r = 0; r < 4; r++) {
        float v = rintf((float)acc[i][j][r] * rs);
        v = fminf(127.f, fmaxf(-128.f, v));
        out[(size_t)(row0 + r) * NDIM + col] = v;
      }
    }
  }
}

extern "C" void kernel_launch(void* const* d_in, const int* in_sizes, int n_in,
                              void* d_out, int out_size, void* d_ws, size_t ws_size,
                              hipStream_t stream) {
  const int* x32 = (const int*)d_in[0];
  const int* w32 = (const int*)d_in[1];
  const float* sx = (const float*)d_in[2];
  const float* sw = (const float*)d_in[3];
  const float* sy = (const float*)d_in[4];
  float* out = (float*)d_out;
  float* tail = out + (size_t)MDIM * NDIM;

  uint8_t* x8f = (uint8_t*)d_ws;
  uint8_t* w8f = x8f + (size_t)MDIM * KDIM;

  const int total = (MDIM / 16) * KDIM + (NDIM / 16) * KDIM;  // 3,145,728
  pack_kernel<<<total / 256, 256, 0, stream>>>(x32, w32, sy, x8f, w8f, tail);

  const int nblocks = (MDIM / BM) * (NDIM / BN);  // 512
  gemm_kernel<<<nblocks, 256, 0, stream>>>(x8f, w8f, sx, sw, sy, out);
}

// Round 7
// 185.780 us; speedup vs baseline: 1.1152x; 1.1152x over previous
//
#include <hip/hip_runtime.h>
#include <cstdint>

// y = clip(round((x @ W^T) * (sx*sw/sy)), -128, 127), M=8192 N=4096 K=4096 int8.
// Pass 1 (pack): int32 -> int8, permuted to MFMA-fragment-major:
//   layout [rowblk 256][h 0..63 (K/64)][rf 0..15][lane*16], lane = kl*16+fr:
//   lane holds rows rf*16+fr, K-bytes h*64 + kl*16..+15 -- the exact
//   mfma_i32_16x16x64_i8 operand order. So a fragment IS a coalesced
//   global_load_dwordx4 at base + h*16K + rf*1K + lane*16.
// Pass 2 (GEMM): NO LDS AT ALL. Evidence from rounds 3-6: LDS pipe time
//   (reads + DMA writes, ~2300 cyc/tile) never overlaps MFMA (~2600) under
//   any barrier/phase/private-ring schedule -- serial sum every time.
//   Instead: 4 waves (2x2), 128x128 output per wave, fragments loaded
//   straight from L2 into registers, depth-1 double buffer (loads for h+1
//   issued ~1300 cyc before use). Addresses are SGPR-base + lane*16 + imm.
//   Per h-tile per CU: 64KB from L2 over ~1306 cyc MFMA = 50 B/cyc < 56 L2
//   ceiling; pair-waves share lines (L1 dedup). acc 8x8xv4i -> AGPRs.

#define MDIM 8192
#define NDIM 4096
#define KDIM 4096
#define BM 256
#define BN 256
#define NH 64  // K half-tiles of 64 bytes

typedef int v4i __attribute__((ext_vector_type(4)));

__device__ __forceinline__ uint32_t pack4(int a, int b, int c, int d) {
  return (uint32_t)(a & 0xFF) | ((uint32_t)(b & 0xFF) << 8) |
         ((uint32_t)(c & 0xFF) << 16) | ((uint32_t)(d & 0xFF) << 24);
}

// ---------- pack: gather int32 -> fragment-major int8 + scale_y tail ----------
__global__ __launch_bounds__(256) void pack_kernel(
    const int* __restrict__ x32, const int* __restrict__ w32,
    const float* __restrict__ sy, uint8_t* __restrict__ x8f,
    uint8_t* __restrict__ w8f, float* __restrict__ tail) {
  const int t = blockIdx.x * 256 + threadIdx.x;
  if (t < NDIM) tail[t] = sy[t];
  const int NXC = (MDIM / 16) * KDIM;  // 2,097,152 16B-chunks for x
  const int NWC = (NDIM / 16) * KDIM;  // 1,048,576 for w
  if (t >= NXC + NWC) return;
  const int* src;
  uint8_t* dst;
  int chunk;
  if (t < NXC) {
    chunk = t;
    src = x32;
    dst = x8f;
  } else {
    chunk = t - NXC;
    src = w32;
    dst = w8f;
  }
  // chunk -> [mb][h][rf][lane], 16B per lane slot
  const int lpos = chunk & 63;       // lane
  const int rf = (chunk >> 6) & 15;  // 16-row fragment
  const int h = (chunk >> 10) & 63;  // K-half-tile (64 bytes)
  const int mb = chunk >> 16;        // 256-row block
  const int kl = lpos >> 4, fr = lpos & 15;
  const int r = mb * 256 + rf * 16 + fr;
  const int k0 = h * 64 + kl * 16;
  const int* s = src + (size_t)r * KDIM + k0;  // 16 int32 = 64B line
  v4i a0 = *(const v4i*)(s + 0);
  v4i a1 = *(const v4i*)(s + 4);
  v4i a2 = *(const v4i*)(s + 8);
  v4i a3 = *(const v4i*)(s + 12);
  v4i o;
  o[0] = (int)pack4(a0[0], a0[1], a0[2], a0[3]);
  o[1] = (int)pack4(a1[0], a1[1], a1[2], a1[3]);
  o[2] = (int)pack4(a2[0], a2[1], a2[2], a2[3]);
  o[3] = (int)pack4(a3[0], a3[1], a3[2], a3[3]);
  *(v4i*)(dst + (size_t)chunk * 16) = o;  // linear, fully coalesced
}

// ---------- main GEMM: LDS-free, register double-buffered ---------------------
// 256 threads = 4 waves (2M x 2N), per-wave output 128x128, acc 8x8 frags.
__global__ __launch_bounds__(256, 1) void gemm_kernel(
    const uint8_t* __restrict__ A8, const uint8_t* __restrict__ B8,
    const float* __restrict__ sxp, const float* __restrict__ swp,
    const float* __restrict__ syp, float* __restrict__ out) {
  const int tid = threadIdx.x;
  const int lane = tid & 63;
  const int wave = tid >> 6;  // 0..3

  // XCD-aware swizzle: nwg = 512 (divisible by 8 -> bijective)
  const int wg = ((int)blockIdx.x % 8) * 64 + (int)blockIdx.x / 8;
  const int mb = wg >> 4;  // 0..31
  const int nb = wg & 15;  // 0..15

  const int wm2 = wave >> 1;  // M-half
  const int wn2 = wave & 1;   // N-half

  // wave's fragment streams (already in MFMA operand order)
  const uint8_t* Asrc =
      A8 + ((size_t)mb << 20) + ((size_t)wm2 << 13) + (size_t)lane * 16;
  const uint8_t* Bsrc =
      B8 + ((size_t)nb << 20) + ((size_t)wn2 << 13) + (size_t)lane * 16;

  v4i acc[8][8];
#pragma unroll
  for (int i = 0; i < 8; i++)
#pragma unroll
    for (int j = 0; j < 8; j++) acc[i][j] = (v4i){0, 0, 0, 0};

  v4i a0[8], b0[8], a1[8], b1[8];

  auto load = [&](v4i(&a)[8], v4i(&b)[8], int h) {
    const uint8_t* pa = Asrc + ((size_t)h << 14);
    const uint8_t* pb = Bsrc + ((size_t)h << 14);
#pragma unroll
    for (int i = 0; i < 8; i++) a[i] = *(const v4i*)(pa + (i << 10));
#pragma unroll
    for (int j = 0; j < 8; j++) b[j] = *(const v4i*)(pb + (j << 10));
  };
  auto mfma = [&](v4i(&a)[8], v4i(&b)[8]) {
#pragma unroll
    for (int i = 0; i < 8; i++)
#pragma unroll
      for (int j = 0; j < 8; j++)
        acc[i][j] =
            __builtin_amdgcn_mfma_i32_16x16x64_i8(a[i], b[j], acc[i][j], 0, 0, 0);
  };

  load(a0, b0, 0);
  load(a1, b1, 1);

  for (int h = 0; h < NH - 2; h += 2) {
    mfma(a0, b0);
    load(a0, b0, h + 2);  // issued ~1300 cyc before use
    mfma(a1, b1);
    load(a1, b1, h + 3);
  }
  mfma(a0, b0);  // h = 62
  mfma(a1, b1);  // h = 63

  // epilogue: requantize, round-half-even, clip, store float
  const float s = sxp[0] * swp[0];
  const int kl = lane >> 4;
  const int fr = lane & 15;
  const int wrow = mb * 256 + wm2 * 128;
  const int wcol = nb * 256 + wn2 * 128;
#pragma unroll
  for (int j = 0; j < 8; j++) {
    const int col = wcol + j * 16 + fr;
    const float rs = s / syp[col];
#pragma unroll
    for (int i = 0; i < 8; i++) {
      const int row0 = wrow + i * 16 + kl * 4;
#pragma unroll
      for (int r = 0; r < 4; r++) {
        float v = rintf((float)acc[i][j][r] * rs);
        v = fminf(127.f, fmaxf(-128.f, v));
        out[(size_t)(row0 + r) * NDIM + col] = v;
      }
    }
  }
}

extern "C" void kernel_launch(void* const* d_in, const int* in_sizes, int n_in,
                              void* d_out, int out_size, void* d_ws, size_t ws_size,
                              hipStream_t stream) {
  const int* x32 = (const int*)d_in[0];
  const int* w32 = (const int*)d_in[1];
  const float* sx = (const float*)d_in[2];
  const float* sw = (const float*)d_in[3];
  const float* sy = (const float*)d_in[4];
  float* out = (float*)d_out;
  float* tail = out + (size_t)MDIM * NDIM;

  uint8_t* x8f = (uint8_t*)d_ws;
  uint8_t* w8f = x8f + (size_t)MDIM * KDIM;

  const int total = (MDIM / 16) * KDIM + (NDIM / 16) * KDIM;  // 3,145,728
  pack_kernel<<<total / 256, 256, 0, stream>>>(x32, w32, sy, x8f, w8f, tail);

  const int nblocks = (MDIM / BM) * (NDIM / BN);  // 512
  gemm_kernel<<<nblocks, 256, 0, stream>>>(x8f, w8f, sx, sw, sy, out);
}

// Round 8
// 184.433 us; speedup vs baseline: 1.1233x; 1.0073x over previous
//
#include <hip/hip_runtime.h>
#include <cstdint>

// y = clip(round((x @ W^T) * (sx*sw/sy)), -128, 127), M=8192 N=4096 K=4096 int8.
// Pass 1 (pack): int32 -> int8, fragment-major: [mb 256rows][h 0..63 (K/64B)]
//   [rf 0..15][lane*16], lane = kl*16+fr -> rows rf*16+fr, K h*64+kl*16..+15
//   (exact mfma_i32_16x16x64_i8 operand order; SQ_LDS_BANK_CONFLICT = 0).
// Pass 2 (GEMM): 256x256 tile, 8 waves (2Mx4N, 128x64 each), m201-style
//   8-phase schedule per 128B K-tile. KEY FIX vs round 4: <=6 ds_reads per
//   phase (quadrant operand reuse: 6,2,4,0 per kh-half) so the CU-wide LDS
//   drain (<=48 reads ~290cyc) fits under the 16-MFMA/SIMD cluster (~326cyc).
//   LDS = 4 half-slots of 32KB (ring-2 tiles); 1 stage-load per phase;
//   vmcnt(4) ONLY at phases 4 and 8 (4 loads always in flight, never 0
//   mid-loop); lgkmcnt(0)+sched_barrier after each barrier; setprio around
//   MFMA clusters; wait-then-barrier for cross-wave DMA visibility.

#define MDIM 8192
#define NDIM 4096
#define KDIM 4096
#define BM 256
#define BN 256
#define NT 32  // 128B K-tiles

typedef int v4i __attribute__((ext_vector_type(4)));

#define FENCE() asm volatile("" ::: "memory")
#define BARX()                    \
  do {                            \
    FENCE();                      \
    __builtin_amdgcn_s_barrier(); \
    FENCE();                      \
  } while (0)
#define LGKM0()                                        \
  do {                                                 \
    asm volatile("s_waitcnt lgkmcnt(0)" ::: "memory"); \
    __builtin_amdgcn_sched_barrier(0);                 \
  } while (0)

__device__ __forceinline__ uint32_t pack4(int a, int b, int c, int d) {
  return (uint32_t)(a & 0xFF) | ((uint32_t)(b & 0xFF) << 8) |
         ((uint32_t)(c & 0xFF) << 16) | ((uint32_t)(d & 0xFF) << 24);
}

// ---------- pack: gather int32 -> fragment-major int8 + scale_y tail ----------
__global__ __launch_bounds__(256) void pack_kernel(
    const int* __restrict__ x32, const int* __restrict__ w32,
    const float* __restrict__ sy, uint8_t* __restrict__ x8f,
    uint8_t* __restrict__ w8f, float* __restrict__ tail) {
  const int t = blockIdx.x * 256 + threadIdx.x;
  if (t < NDIM) tail[t] = sy[t];
  const int NXC = (MDIM / 16) * KDIM;
  const int NWC = (NDIM / 16) * KDIM;
  if (t >= NXC + NWC) return;
  const int* src;
  uint8_t* dst;
  int chunk;
  if (t < NXC) {
    chunk = t;
    src = x32;
    dst = x8f;
  } else {
    chunk = t - NXC;
    src = w32;
    dst = w8f;
  }
  const int lpos = chunk & 63;
  const int rf = (chunk >> 6) & 15;
  const int h = (chunk >> 10) & 63;
  const int mb = chunk >> 16;
  const int kl = lpos >> 4, fr = lpos & 15;
  const int r = mb * 256 + rf * 16 + fr;
  const int k0 = h * 64 + kl * 16;
  const int* s = src + (size_t)r * KDIM + k0;
  v4i a0 = *(const v4i*)(s + 0);
  v4i a1 = *(const v4i*)(s + 4);
  v4i a2 = *(const v4i*)(s + 8);
  v4i a3 = *(const v4i*)(s + 12);
  v4i o;
  o[0] = (int)pack4(a0[0], a0[1], a0[2], a0[3]);
  o[1] = (int)pack4(a1[0], a1[1], a1[2], a1[3]);
  o[2] = (int)pack4(a2[0], a2[1], a2[2], a2[3]);
  o[3] = (int)pack4(a3[0], a3[1], a3[2], a3[3]);
  *(v4i*)(dst + (size_t)chunk * 16) = o;
}

// ---------- main GEMM: 8-phase m201-style schedule -----------------------------
// 512 threads = 8 waves (2M x 4N), per-wave output 128x64, acc 8x4 frags.
// LDS: 4 half-slots of 32KB: slot(t,kh) = (t&1)*64K + kh*32K; A 16K | B 16K.
__global__ __launch_bounds__(512, 2) void gemm_kernel(
    const uint8_t* __restrict__ A8, const uint8_t* __restrict__ B8,
    const float* __restrict__ sxp, const float* __restrict__ swp,
    const float* __restrict__ syp, float* __restrict__ out) {
  __shared__ __align__(16) uint8_t lds[131072];

  const int tid = threadIdx.x;
  const int lane = tid & 63;
  const int wave = tid >> 6;

  // XCD-aware swizzle: nwg = 512 (divisible by 8 -> bijective)
  const int wg = ((int)blockIdx.x % 8) * 64 + (int)blockIdx.x / 8;
  const int mb = wg >> 4;  // 0..31
  const int nb = wg & 15;  // 0..15

  const int wm2 = wave >> 2;  // 0..1
  const int wn4 = wave & 3;   // 0..3

  const uint8_t* Abase = A8 + ((size_t)mb << 20);
  const uint8_t* Bbase = B8 + ((size_t)nb << 20);

  const uint32_t tid16 = (uint32_t)tid * 16;
  const uint32_t lane16 = (uint32_t)lane * 16;
  const uint32_t aoff = (uint32_t)(wm2 * 8) << 10;
  const uint32_t boff = (uint32_t)(wn4 * 4) << 10;

  v4i acc[8][4];
#pragma unroll
  for (int i = 0; i < 8; i++)
#pragma unroll
    for (int j = 0; j < 4; j++) acc[i][j] = (v4i){0, 0, 0, 0};

  auto gload = [&](const uint8_t* src, uint32_t ldsoff) {
    __builtin_amdgcn_global_load_lds(
        (const __attribute__((address_space(1))) void*)src,
        (__attribute__((address_space(3))) void*)(lds + ldsoff), 16, 0, 0);
  };
  // load r (0..3) of half (t,kh): r<2 -> A-half, else B-half (8KB pieces)
  auto stage1 = [&](int t, int kh, int r) {
    const uint8_t* src = (r < 2 ? Abase : Bbase) + ((size_t)(2 * t + kh) << 14) +
                         (uint32_t)((r & 1) * 8192) + tid16;
    const uint32_t dst = (uint32_t)(t & 1) * 65536u + (uint32_t)kh * 32768u +
                         (uint32_t)((r >> 1) * 16384 + (r & 1) * 8192) + tid16;
    gload(src, dst);
  };

  // prologue: halves (0,kh0) then (0,kh1), 8 loads in flight
#pragma unroll
  for (int r = 0; r < 4; ++r) stage1(0, 0, r);
#pragma unroll
  for (int r = 0; r < 4; ++r) stage1(0, 1, r);
  asm volatile("s_waitcnt vmcnt(4)" ::: "memory");  // kh0(0) landed
  BARX();

  for (int t = 0; t < NT; ++t) {
    const bool pre = (t + 1 < NT);
#pragma unroll
    for (int kh = 0; kh < 2; ++kh) {
      const uint8_t* SA = lds + (uint32_t)(t & 1) * 65536u + (uint32_t)kh * 32768u;
      const uint8_t* SB = SA + 16384u;
      v4i af[4], ag[4], bf[4];

      // ---- phase 1: reads af0-3, bf0-1 (6); MFMA acc[0-3][0-1] ----
#pragma unroll
      for (int i = 0; i < 4; ++i)
        af[i] = *(const v4i*)(SA + aoff + (i << 10) + lane16);
#pragma unroll
      for (int j = 0; j < 2; ++j)
        bf[j] = *(const v4i*)(SB + boff + (j << 10) + lane16);
      if (pre) stage1(t + 1, kh, 0);
      BARX();
      LGKM0();
      __builtin_amdgcn_s_setprio(1);
#pragma unroll
      for (int i = 0; i < 4; ++i)
#pragma unroll
        for (int j = 0; j < 2; ++j)
          acc[i][j] =
              __builtin_amdgcn_mfma_i32_16x16x64_i8(af[i], bf[j], acc[i][j], 0, 0, 0);
      __builtin_amdgcn_s_setprio(0);
      BARX();

      // ---- phase 2: reads bf2-3 (2); MFMA acc[0-3][2-3] ----
#pragma unroll
      for (int j = 2; j < 4; ++j)
        bf[j] = *(const v4i*)(SB + boff + (j << 10) + lane16);
      if (pre) stage1(t + 1, kh, 1);
      BARX();
      LGKM0();
      __builtin_amdgcn_s_setprio(1);
#pragma unroll
      for (int i = 0; i < 4; ++i)
#pragma unroll
        for (int j = 2; j < 4; ++j)
          acc[i][j] =
              __builtin_amdgcn_mfma_i32_16x16x64_i8(af[i], bf[j], acc[i][j], 0, 0, 0);
      __builtin_amdgcn_s_setprio(0);
      BARX();

      // ---- phase 3: reads af4-7 (4); MFMA acc[4-7][2-3] ----
#pragma unroll
      for (int i = 0; i < 4; ++i)
        ag[i] = *(const v4i*)(SA + aoff + ((4 + i) << 10) + lane16);
      if (pre) stage1(t + 1, kh, 2);
      BARX();
      LGKM0();
      __builtin_amdgcn_s_setprio(1);
#pragma unroll
      for (int i = 0; i < 4; ++i)
#pragma unroll
        for (int j = 2; j < 4; ++j)
          acc[4 + i][j] =
              __builtin_amdgcn_mfma_i32_16x16x64_i8(ag[i], bf[j], acc[4 + i][j], 0, 0, 0);
      __builtin_amdgcn_s_setprio(0);
      BARX();

      // ---- phase 4: 0 reads; MFMA acc[4-7][0-1]; counted vmcnt ----
      if (pre) stage1(t + 1, kh, 3);
      BARX();
      __builtin_amdgcn_s_setprio(1);
#pragma unroll
      for (int i = 0; i < 4; ++i)
#pragma unroll
        for (int j = 0; j < 2; ++j)
          acc[4 + i][j] =
              __builtin_amdgcn_mfma_i32_16x16x64_i8(ag[i], bf[j], acc[4 + i][j], 0, 0, 0);
      __builtin_amdgcn_s_setprio(0);
      // end of kh-half: ensure the half needed next is landed.
      // kh==0: next reads kh1(t)  -> oldest outstanding 4 must drain.
      // kh==1: next reads kh0(t+1)-> likewise. Always 8 outstanding when pre.
      if (pre)
        asm volatile("s_waitcnt vmcnt(4)" ::: "memory");
      else if (kh == 0)
        asm volatile("s_waitcnt vmcnt(0)" ::: "memory");  // last tile: kh1 only
      BARX();
    }
  }

  // epilogue: requantize, round-half-even, clip, store float
  const float s = sxp[0] * swp[0];
  const int kl = lane >> 4;
  const int fr = lane & 15;
  const int wrow = mb * 256 + wm2 * 128;
  const int wcol = nb * 256 + wn4 * 64;
#pragma unroll
  for (int j = 0; j < 4; j++) {
    const int col = wcol + j * 16 + fr;
    const float rs = s / syp[col];
#pragma unroll
    for (int i = 0; i < 8; i++) {
      const int row0 = wrow + i * 16 + kl * 4;
#pragma unroll
      for (int r = 0; r < 4; r++) {
        float v = rintf((float)acc[i][j][r] * rs);
        v = fminf(127.f, fmaxf(-128.f, v));
        out[(size_t)(row0 + r) * NDIM + col] = v;
      }
    }
  }
}

extern "C" void kernel_launch(void* const* d_in, const int* in_sizes, int n_in,
                              void* d_out, int out_size, void* d_ws, size_t ws_size,
                              hipStream_t stream) {
  const int* x32 = (const int*)d_in[0];
  const int* w32 = (const int*)d_in[1];
  const float* sx = (const float*)d_in[2];
  const float* sw = (const float*)d_in[3];
  const float* sy = (const float*)d_in[4];
  float* out = (float*)d_out;
  float* tail = out + (size_t)MDIM * NDIM;

  uint8_t* x8f = (uint8_t*)d_ws;
  uint8_t* w8f = x8f + (size_t)MDIM * KDIM;

  const int total = (MDIM / 16) * KDIM + (NDIM / 16) * KDIM;  // 3,145,728
  pack_kernel<<<total / 256, 256, 0, stream>>>(x32, w32, sy, x8f, w8f, tail);

  const int nblocks = (MDIM / BM) * (NDIM / BN);  // 512
  gemm_kernel<<<nblocks, 512, 0, stream>>>(x8f, w8f, sx, sw, sy, out);
}